// Round 7
// baseline (523.586 us; speedup 1.0000x reference)
//
#include <hip/hip_runtime.h>
#include <hip/hip_bf16.h>
#include <stdint.h>

// GCN pose: fused per-sample chain. 64*243=15552 samples, 17 joints, hidden 256, 4 layers.
// Round 7: round-6 structure (h double-buffered bf16, hold residual in f32 regs,
// MFMA out-projection on wave0, 1 barrier/layer) with the half-swap primitive
// reverted to round-5-proven __shfl_xor(32) (permlane32_swap direction suspect).

#define J17   17
#define HID   256
#define NLAY  4
#define NSAMP 15552
#define SPW   3
#define RUSE  51         // SPW*17 used rows
#define RPAD  64         // padded rows (2 row-tiles of 32)
#define NWG   5184       // NSAMP/SPW exactly

typedef __attribute__((ext_vector_type(4)))  short  short4v;
typedef __attribute__((ext_vector_type(8)))  short  short8;
typedef __attribute__((ext_vector_type(16))) float  float16;

static constexpr int OFS[18] = {0,3,6,9,11,13,17,21,24,27,29,31,35,39,42,45,47,49};
static constexpr int NBRF[49] = {
  0,1,2,  1,0,3,  2,0,4,  3,1,  4,2,
  5,6,7,11,  6,5,8,12,  7,5,9,  8,6,10,  9,7,  10,8,
  11,5,12,13, 12,6,11,14, 13,11,15, 14,12,16, 15,13, 16,14};

__device__ __forceinline__ unsigned short f2bf(float f){
  return __bfloat16_as_ushort(__float2bfloat16(f));   // v_cvt, RNE
}
__device__ __forceinline__ float bf2f(unsigned short b){
  return __builtin_bit_cast(float, ((unsigned)b) << 16);
}

// ---------------- prep ----------------
// pret_b (1 MB): [t(64)][hl(2)][kh(2)][c(256)][j(8)], value = split(W[t>>4][k][c], hl),
//                k = (t&15)*16 + kh*8 + j
// pret_in (8 KB): [kh(2)][c(256)][j(8)] = bf16(w_in[k][c]), k = kh*8+j (<3 else 0)
// pret_out (32 KB): [hl(2)][ks(16)][kh(2)][col(32)][j(8)] = split(w_out[k][col], hl),
//                k = ks*16+kh*8+j, col<3 else 0
__global__ __launch_bounds__(256)
void gcn_prep(const float* __restrict__ adj, const float* __restrict__ Ws,
              const float* __restrict__ w_in, const float* __restrict__ w_out,
              float* __restrict__ Ahat, unsigned short* __restrict__ pret_in,
              unsigned short* __restrict__ pret_out, unsigned short* __restrict__ pret_b)
{
  if (blockIdx.x < 1024){
    const int e  = blockIdx.x*256 + threadIdx.x;
    const int j  = e & 7, cc = (e >> 3) & 255, khh = (e >> 11) & 1, t = e >> 12;
    const int k  = (t & 15)*16 + khh*8 + j;
    const float w = Ws[(t >> 4)*65536 + k*256 + cc];
    const unsigned short hi = f2bf(w);
    const int base = (t*4 + khh)*2048 + cc*8 + j;
    pret_b[base]        = hi;
    pret_b[base + 4096] = f2bf(w - bf2f(hi));
  } else {
    const int tid = threadIdx.x;
    for (int e = tid; e < 4096; e += 256){
      const int j = e & 7, cc = (e >> 3) & 255, khh = e >> 11;
      const int k = khh*8 + j;
      pret_in[e] = (k < 3) ? f2bf(w_in[k*256 + cc]) : (unsigned short)0;
    }
    for (int e = tid; e < 8192; e += 256){
      const int j = e & 7, col = (e >> 3) & 31, khh = (e >> 8) & 1, ks = e >> 9;
      const int k = ks*16 + khh*8 + j;
      const float w = (col < 3) ? w_out[k*3 + col] : 0.0f;
      const unsigned short hi = f2bf(w);
      const int idx = ((ks*2 + khh)*32 + col)*8 + j;
      pret_out[idx]        = hi;
      pret_out[idx + 8192] = f2bf(w - bf2f(hi));
    }
    for (int t = tid; t < 289; t += 256){
      const int j = t/17, k2 = t%17;
      float dj = 1e-5f, dk = 1e-5f;
      for (int m=0;m<17;++m){ dj += adj[j*17+m]; dk += adj[k2*17+m]; }
      Ahat[t] = adj[t] / (sqrtf(dj)*sqrtf(dk));
    }
  }
}

// C-fragment decode: row n = (q&3) + 8*((q>>3... see below) ; q = (n&3)|(((n>>3)&3)<<2)
#define QIDX(n) (((n)&3) | ((((n)>>3)&3)<<2))

__global__ __launch_bounds__(512, 4)
void gcn_main(const float* __restrict__ x, const float* __restrict__ b_in,
              const float* __restrict__ bs, const float* __restrict__ b_out,
              const float* __restrict__ Ahat,
              const unsigned short* __restrict__ pret_in,
              const unsigned short* __restrict__ pret_out,
              const unsigned short* __restrict__ pret_b,
              float* __restrict__ out)
{
  __shared__ unsigned short h[2*RPAD*HID];          // 64 KB: two 32 KB buffers
  unsigned short* xt = h + RPAD*HID;                // x-tile aliases buf1 (dead by mix0)

  const int tid  = threadIdx.x;
  const int lane = tid & 63;
  const int wid  = tid >> 6;
  const int kh   = lane >> 5;
  const int l31  = lane & 31;
  const int c    = wid*32 + l31;
  const int wg   = blockIdx.x;

  const char* h_b = (const char*)h;

  // ---- B prefetch: frags straight from global (L2-resident) ----
  const unsigned short* pb = pret_b + kh*2048 + c*8;
  short8 BA[2], BB[2];                              // {Whi, Wlo} for one k-step
  auto loadB = [&](int t, short8* d){
    const unsigned short* p = pb + t*8192;
    d[0] = *(const short8*)p;
    d[1] = *(const short8*)(p + 4096);
  };
  loadB(0, BA);
  const short8 BI = *(const short8*)(pret_in + kh*2048 + c*8);

  // sparse A_hat coefficients -> SGPRs
  float Ac[49];
#pragma unroll
  for (int j=0;j<17;++j){
#pragma unroll
    for (int t=OFS[j]; t<OFS[j+1]; ++t){
      const float a = Ahat[j*17 + NBRF[t]];
      Ac[t] = __builtin_bit_cast(float,
                __builtin_amdgcn_readfirstlane(__builtin_bit_cast(int, a)));
    }
  }

  // ---- stage x tile (in buf1 alias): xt[r][k], k<3 real else 0 ----
  {
    const int r = tid >> 3, k4 = (tid & 7) << 2;
    short4v v = (short4v)0;
    if (r < RUSE && k4 == 0){
      const int s = r/17, j = r - s*17;
      const float* xb = x + (size_t)(wg*SPW + s)*51 + j*3;
      v.x = (short)f2bf(xb[0]); v.y = (short)f2bf(xb[1]); v.z = (short)f2bf(xb[2]);
    }
    *(short4v*)(xt + r*32 + k4) = v;
  }
  __syncthreads();

  // ---- input projection as MFMA: hold = x @ w_in + b_in; write bf16 -> buf0 ----
  float16 acc[2];
  float16 hold[2];
  {
    const float bc = b_in[c];
#pragma unroll
    for (int rt=0; rt<2; ++rt)
#pragma unroll
    for (int q=0; q<16; ++q) acc[rt][q] = bc;
#pragma unroll
    for (int rt=0; rt<2; ++rt){
      const short8 Ax = *(const short8*)(xt + (rt*32 + l31)*32 + kh*8);
      acc[rt] = __builtin_amdgcn_mfma_f32_32x32x16_bf16(Ax, BI, acc[rt], 0,0,0);
    }
#pragma unroll
    for (int rt=0; rt<2; ++rt)
#pragma unroll
    for (int q=0; q<16; ++q){
      const int r  = rt*32 + (q&3) + 8*(q>>2) + 4*kh;
      hold[rt][q] = acc[rt][q];
      const int hb = (r << 9) + ((2*c) ^ ((r & 31) << 4));
      h[hb >> 1] = f2bf(acc[rt][q]);
    }
  }
  __syncthreads();

  // ---- layers: read buf[l&1], mix writes buf[(l+1)&1]; ONE barrier per layer ----
#pragma unroll 1
  for (int layer=0; layer<NLAY; ++layer){
    const char* hr = h_b + (size_t)((layer & 1) * (RPAD*HID*2));
#pragma unroll
    for (int rt=0; rt<2; ++rt)
#pragma unroll
    for (int q=0; q<16; ++q) acc[rt][q] = 0.0f;

    auto step = [&](int ksl, const short8* B){
      short8 Ah[2];
#pragma unroll
      for (int rt=0; rt<2; ++rt){
        const int r   = rt*32 + l31;
        const int off = (r << 9) + ((ksl*32 + kh*16) ^ ((r & 31) << 4));
        Ah[rt] = *(const short8*)(hr + off);
      }
#pragma unroll
      for (int rt=0; rt<2; ++rt){
        acc[rt] = __builtin_amdgcn_mfma_f32_32x32x16_bf16(Ah[rt], B[0], acc[rt], 0,0,0);
        acc[rt] = __builtin_amdgcn_mfma_f32_32x32x16_bf16(Ah[rt], B[1], acc[rt], 0,0,0);
      }
    };

    const int t0 = layer*16;
#pragma unroll
    for (int ks=0; ks<16; ks+=2){
      loadB(t0 + ks + 1, BB);
      step(ks, BA);
      loadB(min(t0 + ks + 2, 63), BA);
      step(ks + 1, BB);
    }

    // ---- graph mix + bias + relu + residual -> write OTHER buffer ----
    {
      const float bsv = bs[layer*256 + c];
      unsigned short* hw = h + (((layer & 1) ^ 1) * RPAD*HID);
#pragma unroll
      for (int s=0; s<SPW; ++s){
        float sup[17];                         // lane-uniform row values (this sample)
        // build sup via shfl_xor(32): own slot holds row n+4*kh, partner the other
#pragma unroll
        for (int nn=0; nn<17; ++nn){
          const int n = 17*s + nn;
          if (((n>>2)&1)==0){
            const float own = acc[n>>5][QIDX(n)];
            const float oth = __shfl_xor(own, 32, 64);
            sup[nn] = kh ? oth : own;                   // row n
            if (nn+4 < 17) sup[nn+4] = kh ? own : oth;  // row n+4
          } else if (nn < 4){                  // base row in previous sample
            const float own = acc[(n-4)>>5][QIDX(n-4)];
            const float oth = __shfl_xor(own, 32, 64);
            sup[nn] = kh ? own : oth;                   // row n
          }
        }
#pragma unroll
        for (int nn=0; nn<17; ++nn){
          const int n = 17*s + nn;
          const int hbit = (n>>2)&1;
          if (hbit==0 && nn+4<17){
            // pair (n, n+4): same (rt,q) slot; my row = n + 4*kh
            float v0 = bsv, v1 = bsv;
#pragma unroll
            for (int t=OFS[nn]; t<OFS[nn+1]; ++t)     v0 += Ac[t]*sup[NBRF[t]];
#pragma unroll
            for (int t=OFS[nn+4]; t<OFS[nn+5]; ++t)   v1 += Ac[t]*sup[NBRF[t]];
            const float vm = kh ? v1 : v0;
            const int rt = n>>5, q = QIDX(n);
            const float o = fmaxf(vm, 0.0f) + hold[rt][q];
            hold[rt][q] = o;
            const int rm  = n + 4*kh;
            const int off = (rm << 9) + ((2*c) ^ ((rm & 31) << 4));
            hw[off >> 1] = f2bf(o);
          } else if ((hbit==0 && nn+4>=17) || (hbit==1 && nn<4)){
            // solo row n, owned by half hbit
            float v0 = bsv;
#pragma unroll
            for (int t=OFS[nn]; t<OFS[nn+1]; ++t) v0 += Ac[t]*sup[NBRF[t]];
            if (kh == hbit){
              const int rt = (n - 4*hbit) >> 5, q = QIDX(n);
              const float o = fmaxf(v0, 0.0f) + hold[rt][q];
              hold[rt][q] = o;
              const int off = (n << 9) + ((2*c) ^ ((n & 31) << 4));
              hw[off >> 1] = f2bf(o);
            }
          }
          // else: partner row of an in-sample pair — already handled
        }
      }
    }
    __syncthreads();
  }

  // ---- output projection as MFMA on wave 0: y = h @ w_out + b_out ----
  if (wid == 0){
    const float bo = (l31 < 3) ? b_out[l31] : 0.0f;
    float16 y[2];
#pragma unroll
    for (int rt=0; rt<2; ++rt)
#pragma unroll
    for (int q=0; q<16; ++q) y[rt][q] = bo;

    const unsigned short* po = pret_out + kh*256 + l31*8;
#pragma unroll
    for (int ks=0; ks<16; ++ks){
      const short8 Bh = *(const short8*)(po + ks*512);
      const short8 Bl = *(const short8*)(po + 8192 + ks*512);
      short8 Ah[2];
#pragma unroll
      for (int rt=0; rt<2; ++rt){
        const int r   = rt*32 + l31;
        const int off = (r << 9) + ((ks*32 + kh*16) ^ ((r & 31) << 4));
        Ah[rt] = *(const short8*)(h_b + off);          // final h is buf0
      }
#pragma unroll
      for (int rt=0; rt<2; ++rt){
        y[rt] = __builtin_amdgcn_mfma_f32_32x32x16_bf16(Ah[rt], Bh, y[rt], 0,0,0);
        y[rt] = __builtin_amdgcn_mfma_f32_32x32x16_bf16(Ah[rt], Bl, y[rt], 0,0,0);
      }
    }
#pragma unroll
    for (int rt=0; rt<2; ++rt)
#pragma unroll
    for (int q=0; q<16; ++q){
      const int r0 = rt*32 + (q&3) + 8*(q>>2);
      const int r  = r0 + 4*kh;
      if (r < RUSE && l31 < 3){
        const int s = r/17, jj = r - s*17;
        out[((size_t)(wg*SPW + s)*17 + jj)*3 + l31] = y[rt][q];
      }
    }
  }
}

extern "C" void kernel_launch(void* const* d_in, const int* in_sizes, int n_in,
                              void* d_out, int out_size, void* d_ws, size_t ws_size,
                              hipStream_t stream)
{
  const float* x     = (const float*)d_in[0];
  const float* adj   = (const float*)d_in[1];
  const float* w_in  = (const float*)d_in[2];
  const float* b_in  = (const float*)d_in[3];
  const float* Ws    = (const float*)d_in[4];
  const float* bs    = (const float*)d_in[5];
  const float* w_out = (const float*)d_in[6];
  const float* b_out = (const float*)d_in[7];
  float* out = (float*)d_out;

  float*          Ahat     = (float*)d_ws;                               // 4 KB
  unsigned short* pret_in  = (unsigned short*)((char*)d_ws + 4096);     // 8 KB
  unsigned short* pret_out = (unsigned short*)((char*)d_ws + 12288);    // 32 KB
  unsigned short* pret_b   = (unsigned short*)((char*)d_ws + 49152);    // 1 MB

  hipLaunchKernelGGL(gcn_prep, dim3(1025), dim3(256), 0, stream,
                     adj, Ws, w_in, w_out, Ahat, pret_in, pret_out, pret_b);
  hipLaunchKernelGGL(gcn_main, dim3(NWG), dim3(512), 0, stream,
                     x, b_in, bs, b_out, Ahat, pret_in, pret_out, pret_b, out);
}

// Round 8
// 433.317 us; speedup vs baseline: 1.2083x; 1.2083x over previous
//
#include <hip/hip_runtime.h>
#include <hip/hip_bf16.h>
#include <stdint.h>

// GCN pose: fused per-sample chain. 64*243=15552 samples, 17 joints, hidden 256, 4 layers.
// Round 8: round-7 structure (h double-buffered bf16, 1 barrier/layer, MFMA out-proj on
// wave0, shfl_xor half-swap) with hold[] registers REMOVED — residual re-read from the
// read buffer (it holds h_l exactly). Cuts steady-state VGPR liveness ~122 -> ~90 so the
// allocator stops spilling (round 7: 283 MB scratch writes/dispatch).

#define J17   17
#define HID   256
#define NLAY  4
#define NSAMP 15552
#define SPW   3
#define RUSE  51         // SPW*17 used rows
#define RPAD  64         // padded rows (2 row-tiles of 32)
#define NWG   5184       // NSAMP/SPW exactly

typedef __attribute__((ext_vector_type(4)))  short  short4v;
typedef __attribute__((ext_vector_type(8)))  short  short8;
typedef __attribute__((ext_vector_type(16))) float  float16;

static constexpr int OFS[18] = {0,3,6,9,11,13,17,21,24,27,29,31,35,39,42,45,47,49};
static constexpr int NBRF[49] = {
  0,1,2,  1,0,3,  2,0,4,  3,1,  4,2,
  5,6,7,11,  6,5,8,12,  7,5,9,  8,6,10,  9,7,  10,8,
  11,5,12,13, 12,6,11,14, 13,11,15, 14,12,16, 15,13, 16,14};

__device__ __forceinline__ unsigned short f2bf(float f){
  return __bfloat16_as_ushort(__float2bfloat16(f));   // v_cvt, RNE
}
__device__ __forceinline__ float bf2f(unsigned short b){
  return __builtin_bit_cast(float, ((unsigned)b) << 16);
}

// ---------------- prep ----------------
// pret_b (1 MB): [t(64)][hl(2)][kh(2)][c(256)][j(8)], value = split(W[t>>4][k][c], hl),
//                k = (t&15)*16 + kh*8 + j
// pret_in (8 KB): [kh(2)][c(256)][j(8)] = bf16(w_in[k][c]), k = kh*8+j (<3 else 0)
// pret_out (32 KB): [hl(2)][ks(16)][kh(2)][col(32)][j(8)] = split(w_out[k][col], hl),
//                k = ks*16+kh*8+j, col<3 else 0
__global__ __launch_bounds__(256)
void gcn_prep(const float* __restrict__ adj, const float* __restrict__ Ws,
              const float* __restrict__ w_in, const float* __restrict__ w_out,
              float* __restrict__ Ahat, unsigned short* __restrict__ pret_in,
              unsigned short* __restrict__ pret_out, unsigned short* __restrict__ pret_b)
{
  if (blockIdx.x < 1024){
    const int e  = blockIdx.x*256 + threadIdx.x;
    const int j  = e & 7, cc = (e >> 3) & 255, khh = (e >> 11) & 1, t = e >> 12;
    const int k  = (t & 15)*16 + khh*8 + j;
    const float w = Ws[(t >> 4)*65536 + k*256 + cc];
    const unsigned short hi = f2bf(w);
    const int base = (t*4 + khh)*2048 + cc*8 + j;
    pret_b[base]        = hi;
    pret_b[base + 4096] = f2bf(w - bf2f(hi));
  } else {
    const int tid = threadIdx.x;
    for (int e = tid; e < 4096; e += 256){
      const int j = e & 7, cc = (e >> 3) & 255, khh = e >> 11;
      const int k = khh*8 + j;
      pret_in[e] = (k < 3) ? f2bf(w_in[k*256 + cc]) : (unsigned short)0;
    }
    for (int e = tid; e < 8192; e += 256){
      const int j = e & 7, col = (e >> 3) & 31, khh = (e >> 8) & 1, ks = e >> 9;
      const int k = ks*16 + khh*8 + j;
      const float w = (col < 3) ? w_out[k*3 + col] : 0.0f;
      const unsigned short hi = f2bf(w);
      const int idx = ((ks*2 + khh)*32 + col)*8 + j;
      pret_out[idx]        = hi;
      pret_out[idx + 8192] = f2bf(w - bf2f(hi));
    }
    for (int t = tid; t < 289; t += 256){
      const int j = t/17, k2 = t%17;
      float dj = 1e-5f, dk = 1e-5f;
      for (int m=0;m<17;++m){ dj += adj[j*17+m]; dk += adj[k2*17+m]; }
      Ahat[t] = adj[t] / (sqrtf(dj)*sqrtf(dk));
    }
  }
}

// C-fragment decode: row n = (q&3) + 8*((q>>2)&3) + 4*half + 32*rt
#define QIDX(n) (((n)&3) | ((((n)>>3)&3)<<2))

__global__ __launch_bounds__(512, 4)
void gcn_main(const float* __restrict__ x, const float* __restrict__ b_in,
              const float* __restrict__ bs, const float* __restrict__ b_out,
              const float* __restrict__ Ahat,
              const unsigned short* __restrict__ pret_in,
              const unsigned short* __restrict__ pret_out,
              const unsigned short* __restrict__ pret_b,
              float* __restrict__ out)
{
  __shared__ unsigned short h[2*RPAD*HID];          // 64 KB: two 32 KB buffers
  unsigned short* xt = h + RPAD*HID;                // x-tile aliases buf1 (dead by mix0)

  const int tid  = threadIdx.x;
  const int lane = tid & 63;
  const int wid  = tid >> 6;
  const int kh   = lane >> 5;
  const int l31  = lane & 31;
  const int c    = wid*32 + l31;
  const int wg   = blockIdx.x;

  const char* h_b = (const char*)h;

  // ---- B prefetch: frags straight from global (L2-resident) ----
  const unsigned short* pb = pret_b + kh*2048 + c*8;
  short8 BA[2], BB[2];                              // {Whi, Wlo} for one k-step
  auto loadB = [&](int t, short8* d){
    const unsigned short* p = pb + t*8192;
    d[0] = *(const short8*)p;
    d[1] = *(const short8*)(p + 4096);
  };
  loadB(0, BA);
  const short8 BI = *(const short8*)(pret_in + kh*2048 + c*8);

  // sparse A_hat coefficients -> SGPRs
  float Ac[49];
#pragma unroll
  for (int j=0;j<17;++j){
#pragma unroll
    for (int t=OFS[j]; t<OFS[j+1]; ++t){
      const float a = Ahat[j*17 + NBRF[t]];
      Ac[t] = __builtin_bit_cast(float,
                __builtin_amdgcn_readfirstlane(__builtin_bit_cast(int, a)));
    }
  }

  // ---- stage x tile (in buf1 alias): xt[r][k], k<3 real else 0 ----
  {
    const int r = tid >> 3, k4 = (tid & 7) << 2;
    short4v v = (short4v)0;
    if (r < RUSE && k4 == 0){
      const int s = r/17, j = r - s*17;
      const float* xb = x + (size_t)(wg*SPW + s)*51 + j*3;
      v.x = (short)f2bf(xb[0]); v.y = (short)f2bf(xb[1]); v.z = (short)f2bf(xb[2]);
    }
    *(short4v*)(xt + r*32 + k4) = v;
  }
  __syncthreads();

  // ---- input projection as MFMA: h0 = x @ w_in + b_in -> buf0 (bf16) ----
  float16 acc[2];
  {
    const float bc = b_in[c];
#pragma unroll
    for (int rt=0; rt<2; ++rt)
#pragma unroll
    for (int q=0; q<16; ++q) acc[rt][q] = bc;
#pragma unroll
    for (int rt=0; rt<2; ++rt){
      const short8 Ax = *(const short8*)(xt + (rt*32 + l31)*32 + kh*8);
      acc[rt] = __builtin_amdgcn_mfma_f32_32x32x16_bf16(Ax, BI, acc[rt], 0,0,0);
    }
#pragma unroll
    for (int rt=0; rt<2; ++rt)
#pragma unroll
    for (int q=0; q<16; ++q){
      const int r  = rt*32 + (q&3) + 8*(q>>2) + 4*kh;
      const int hb = (r << 9) + ((2*c) ^ ((r & 31) << 4));
      h[hb >> 1] = f2bf(acc[rt][q]);
    }
  }
  __syncthreads();

  // ---- layers: read buf[l&1], mix writes buf[(l+1)&1]; ONE barrier per layer ----
#pragma unroll 1
  for (int layer=0; layer<NLAY; ++layer){
    const char* hr = h_b + (size_t)((layer & 1) * (RPAD*HID*2));
    const unsigned short* hru = (const unsigned short*)hr;
#pragma unroll
    for (int rt=0; rt<2; ++rt)
#pragma unroll
    for (int q=0; q<16; ++q) acc[rt][q] = 0.0f;

    auto step = [&](int ksl, const short8* B){
      short8 Ah[2];
#pragma unroll
      for (int rt=0; rt<2; ++rt){
        const int r   = rt*32 + l31;
        const int off = (r << 9) + ((ksl*32 + kh*16) ^ ((r & 31) << 4));
        Ah[rt] = *(const short8*)(hr + off);
      }
#pragma unroll
      for (int rt=0; rt<2; ++rt){
        acc[rt] = __builtin_amdgcn_mfma_f32_32x32x16_bf16(Ah[rt], B[0], acc[rt], 0,0,0);
        acc[rt] = __builtin_amdgcn_mfma_f32_32x32x16_bf16(Ah[rt], B[1], acc[rt], 0,0,0);
      }
    };

    const int t0 = layer*16;
#pragma unroll
    for (int ks=0; ks<16; ks+=2){
      loadB(t0 + ks + 1, BB);
      step(ks, BA);
      loadB(min(t0 + ks + 2, 63), BA);
      step(ks + 1, BB);
    }

    // ---- graph mix + bias + relu + residual(-from-LDS) -> write OTHER buffer ----
    // residual source: hr still holds h_l at (r,c); concurrent reads only, no race.
    {
      const float bsv = bs[layer*256 + c];
      unsigned short* hw = h + (((layer & 1) ^ 1) * RPAD*HID);
#pragma unroll
      for (int s=0; s<SPW; ++s){
        float sup[17];                         // lane-uniform row values (this sample)
#pragma unroll
        for (int nn=0; nn<17; ++nn){
          const int n = 17*s + nn;
          if (((n>>2)&1)==0){
            const float own = acc[n>>5][QIDX(n)];
            const float oth = __shfl_xor(own, 32, 64);
            sup[nn] = kh ? oth : own;                   // row n
            if (nn+4 < 17) sup[nn+4] = kh ? own : oth;  // row n+4
          } else if (nn < 4){                  // base row in previous sample
            const float own = acc[(n-4)>>5][QIDX(n-4)];
            const float oth = __shfl_xor(own, 32, 64);
            sup[nn] = kh ? own : oth;                   // row n
          }
        }
#pragma unroll
        for (int nn=0; nn<17; ++nn){
          const int n = 17*s + nn;
          const int hbit = (n>>2)&1;
          if (hbit==0 && nn+4<17){
            // pair (n, n+4): same (rt,q) slot; my row = n + 4*kh
            float v0 = bsv, v1 = bsv;
#pragma unroll
            for (int t=OFS[nn]; t<OFS[nn+1]; ++t)     v0 += Ac[t]*sup[NBRF[t]];
#pragma unroll
            for (int t=OFS[nn+4]; t<OFS[nn+5]; ++t)   v1 += Ac[t]*sup[NBRF[t]];
            const float vm = kh ? v1 : v0;
            const int rm  = n + 4*kh;
            const int off = (rm << 9) + ((2*c) ^ ((rm & 31) << 4));
            const float o = fmaxf(vm, 0.0f) + bf2f(hru[off >> 1]);
            hw[off >> 1] = f2bf(o);
          } else if ((hbit==0 && nn+4>=17) || (hbit==1 && nn<4)){
            // solo row n, owned by half hbit
            float v0 = bsv;
#pragma unroll
            for (int t=OFS[nn]; t<OFS[nn+1]; ++t) v0 += Ac[t]*sup[NBRF[t]];
            if (kh == hbit){
              const int off = (n << 9) + ((2*c) ^ ((n & 31) << 4));
              const float o = fmaxf(v0, 0.0f) + bf2f(hru[off >> 1]);
              hw[off >> 1] = f2bf(o);
            }
          }
          // else: partner row of an in-sample pair — already handled
        }
      }
    }
    __syncthreads();
  }

  // ---- output projection as MFMA on wave 0: y = h @ w_out + b_out ----
  if (wid == 0){
    const float bo = (l31 < 3) ? b_out[l31] : 0.0f;
    float16 y[2];
#pragma unroll
    for (int rt=0; rt<2; ++rt)
#pragma unroll
    for (int q=0; q<16; ++q) y[rt][q] = bo;

    const unsigned short* po = pret_out + kh*256 + l31*8;
#pragma unroll
    for (int ks=0; ks<16; ++ks){
      const short8 Bh = *(const short8*)(po + ks*512);
      const short8 Bl = *(const short8*)(po + 8192 + ks*512);
      short8 Ah[2];
#pragma unroll
      for (int rt=0; rt<2; ++rt){
        const int r   = rt*32 + l31;
        const int off = (r << 9) + ((ks*32 + kh*16) ^ ((r & 31) << 4));
        Ah[rt] = *(const short8*)(h_b + off);          // final h is buf0
      }
#pragma unroll
      for (int rt=0; rt<2; ++rt){
        y[rt] = __builtin_amdgcn_mfma_f32_32x32x16_bf16(Ah[rt], Bh, y[rt], 0,0,0);
        y[rt] = __builtin_amdgcn_mfma_f32_32x32x16_bf16(Ah[rt], Bl, y[rt], 0,0,0);
      }
    }
#pragma unroll
    for (int rt=0; rt<2; ++rt)
#pragma unroll
    for (int q=0; q<16; ++q){
      const int r0 = rt*32 + (q&3) + 8*(q>>2);
      const int r  = r0 + 4*kh;
      if (r < RUSE && l31 < 3){
        const int s = r/17, jj = r - s*17;
        out[((size_t)(wg*SPW + s)*17 + jj)*3 + l31] = y[rt][q];
      }
    }
  }
}

extern "C" void kernel_launch(void* const* d_in, const int* in_sizes, int n_in,
                              void* d_out, int out_size, void* d_ws, size_t ws_size,
                              hipStream_t stream)
{
  const float* x     = (const float*)d_in[0];
  const float* adj   = (const float*)d_in[1];
  const float* w_in  = (const float*)d_in[2];
  const float* b_in  = (const float*)d_in[3];
  const float* Ws    = (const float*)d_in[4];
  const float* bs    = (const float*)d_in[5];
  const float* w_out = (const float*)d_in[6];
  const float* b_out = (const float*)d_in[7];
  float* out = (float*)d_out;

  float*          Ahat     = (float*)d_ws;                               // 4 KB
  unsigned short* pret_in  = (unsigned short*)((char*)d_ws + 4096);     // 8 KB
  unsigned short* pret_out = (unsigned short*)((char*)d_ws + 12288);    // 32 KB
  unsigned short* pret_b   = (unsigned short*)((char*)d_ws + 49152);    // 1 MB

  hipLaunchKernelGGL(gcn_prep, dim3(1025), dim3(256), 0, stream,
                     adj, Ws, w_in, w_out, Ahat, pret_in, pret_out, pret_b);
  hipLaunchKernelGGL(gcn_main, dim3(NWG), dim3(512), 0, stream,
                     x, b_in, bs, b_out, Ahat, pret_in, pret_out, pret_b, out);
}